// Round 7
// baseline (315.949 us; speedup 1.0000x reference)
//
#include <hip/hip_runtime.h>
#include <hip/hip_bf16.h>

typedef unsigned short u16;
typedef unsigned int u32;
typedef float f32x4 __attribute__((ext_vector_type(4)));
typedef u16 u16x4 __attribute__((ext_vector_type(4)));
typedef u16 u16x8 __attribute__((ext_vector_type(8)));
typedef __bf16 bf16x8 __attribute__((ext_vector_type(8)));

#define OUT_DIM 4096
#define IN_DIM  4096
#define M_DIM   8192   // 4 * 2048

__device__ __forceinline__ u16 f2bf(float f) {
  u32 u = __builtin_bit_cast(u32, f);
  return (u16)((u + 0x7FFFu + ((u >> 16) & 1u)) >> 16);
}

// ---------------------------------------------------------------------------
// W build: codebook gather + sign unpack + 2-level inverse Haar + scale -> bf16
// ---------------------------------------------------------------------------
__global__ __launch_bounds__(256) void build_w_kernel(
    const float* __restrict__ codebook, const float* __restrict__ scales,
    const int* __restrict__ indices, const int* __restrict__ signs,
    u16* __restrict__ W) {
  __shared__ float c[IN_DIM];
  const int o   = blockIdx.x;
  const int tid = threadIdx.x;
  for (int g = tid; g < IN_DIM / 8; g += 256) {
    const int idx = indices[o * (IN_DIM / 8) + g];
    const int sp  = signs[o * (IN_DIM / 8) + g];
    f32x4 c0 = *(const f32x4*)&codebook[idx * 8];
    f32x4 c1 = *(const f32x4*)&codebook[idx * 8 + 4];
    float v[8] = {c0[0], c0[1], c0[2], c0[3], c1[0], c1[1], c1[2], c1[3]};
#pragma unroll
    for (int j = 0; j < 8; ++j)
      c[g * 8 + j] = ((sp >> j) & 1) ? v[j] : -v[j];
  }
  __syncthreads();
  const float scale = scales[o];
  const float S = 0.70710678118654752440f;
  for (int t = tid; t < IN_DIM / 4; t += 256) {
    float a   = c[t];
    float d1  = c[IN_DIM / 4 + t];
    float d2a = c[IN_DIM / 2 + 2 * t];
    float d2b = c[IN_DIM / 2 + 2 * t + 1];
    float e  = (a + d1) * S;
    float od = (a - d1) * S;
    u16x4 w;
    w[0] = f2bf((e  + d2a) * S * scale);
    w[1] = f2bf((e  - d2a) * S * scale);
    w[2] = f2bf((od + d2b) * S * scale);
    w[3] = f2bf((od - d2b) * S * scale);
    *(u16x4*)&W[(size_t)o * IN_DIM + 4 * t] = w;
  }
}

// ---------------------------------------------------------------------------
// X f32 -> bf16
// ---------------------------------------------------------------------------
__global__ __launch_bounds__(256) void cvt_x_kernel(
    const float* __restrict__ X, u16* __restrict__ Xb) {
  const int stride = gridDim.x * blockDim.x;
  const int n8 = (M_DIM * IN_DIM) / 8;
  for (int i = blockIdx.x * blockDim.x + threadIdx.x; i < n8; i += stride) {
    f32x4 a = *(const f32x4*)&X[(size_t)i * 8];
    f32x4 b = *(const f32x4*)&X[(size_t)i * 8 + 4];
    u16x8 r;
    r[0] = f2bf(a[0]); r[1] = f2bf(a[1]); r[2] = f2bf(a[2]); r[3] = f2bf(a[3]);
    r[4] = f2bf(b[0]); r[5] = f2bf(b[1]); r[6] = f2bf(b[2]); r[7] = f2bf(b[3]);
    *(u16x8*)&Xb[(size_t)i * 8] = r;
  }
}

// ---------------------------------------------------------------------------
// GEMM: C[M][N] f32 = A[M][K](bf16) x B[N][K](bf16, B^T layout).
// R7: 8-phase + REGISTER-PIPELINED fragment reads. Phase p issues the
// ds_reads for phase p+1 (into the alternate reg set), so they drain on the
// LDS port DURING phase p's MFMA cluster; the pre-MFMA wait is a counted
// lgkmcnt(4|8) (this phase's reads stay in flight), not a drain.
// Gates: vmcnt(4) at phases 1,3,5,7 — every region's staging is covered by a
// gate+barrier >=1 phase before its read-ISSUE (re-derived per region for
// steady state, first iter, and the peeled last iter).
// BM=BN=256, BK=64, 8 waves (2Mx4N), ring-2 x 64 KiB LDS, involution swizzle
// o ^= ((o>>3)&0x30) (0 conflicts, proven R2-R6), XCD swizzle, setprio.
// ---------------------------------------------------------------------------
__global__ __launch_bounds__(512, 1) void gemm_bt_kernel(
    const u16* __restrict__ A,   // [M_DIM][K]
    const u16* __restrict__ B,   // [OUT_DIM][K]
    float*     __restrict__ C) { // [M_DIM][OUT_DIM]
  constexpr int K   = IN_DIM;
  constexpr int NT  = K / 64;    // 64 K-tiles (BK=64)
  constexpr int NIT = NT / 2;    // 32 iterations (2 K-tiles each)
  extern __shared__ char smem[]; // 131072 B

  const int tid  = threadIdx.x;
  const int wave = tid >> 6;
  const int lane = tid & 63;

  // XCD-aware bijective swizzle (grid = 512, %8 == 0)
  const int swz = (blockIdx.x & 7) * 64 + (blockIdx.x >> 3);
  const int bm = (swz >> 4) * 256;   // 32 M-blocks
  const int bn = (swz & 15) * 256;   // 16 N-blocks

  const int wr  = (wave >> 2) * 128;  // 2 M-wave-groups
  const int wc  = (wave & 3) * 64;    // 4 N-wave-groups
  const int fr  = lane & 15;
  const int fkB = (lane >> 4) * 16;   // k-frag byte offset within 64B slab row

  // swizzled read offsets within a 16 KiB region (row stride 64 B)
  int offA[2][4], offB[4];
#pragma unroll
  for (int mq = 0; mq < 2; ++mq)
#pragma unroll
    for (int m = 0; m < 4; ++m) {
      int o = (wr + mq * 64 + m * 16 + fr) * 64 + fkB;
      offA[mq][m] = o ^ ((o >> 3) & 0x30);
    }
#pragma unroll
  for (int n = 0; n < 4; ++n) {
    int o = (wc + n * 16 + fr) * 64 + fkB;
    offB[n] = 16384 + (o ^ ((o >> 3) & 0x30));
  }

  // pre-swizzled global stage sources (inverse involution)
  const int d0 = tid * 16,        d1 = 8192 + tid * 16;
  const int l0 = d0 ^ ((d0 >> 3) & 0x30), l1 = d1 ^ ((d1 >> 3) & 0x30);
  const u16* srcA0 = A + (size_t)(bm + (d0 >> 6)) * K + ((l0 & 63) >> 1);
  const u16* srcA1 = A + (size_t)(bm + (d1 >> 6)) * K + ((l1 & 63) >> 1);
  const u16* srcB0 = B + (size_t)(bn + (d0 >> 6)) * K + ((l0 & 63) >> 1);
  const u16* srcB1 = B + (size_t)(bn + (d1 >> 6)) * K + ((l1 & 63) >> 1);
  const int ldsW = wave * 1024;  // wave-uniform dest base (HW adds lane*16)

#define GLD(SRC, DST)                                              \
  __builtin_amdgcn_global_load_lds(                                \
      (const __attribute__((address_space(1))) void*)(SRC),        \
      (__attribute__((address_space(3))) void*)(DST), 16, 0, 0)

  // stage one 16 KiB region-part: part 0 = A-slab, part 1 = B-slab
  auto stagePart = [&](int bufi, int ks, int part, int tile) {
    char* base = smem + bufi * 65536 + ks * 32768 + part * 16384 + ldsW;
    const u16* s0 = (part ? srcB0 : srcA0) + tile * 64 + ks * 32;
    const u16* s1 = (part ? srcB1 : srcA1) + tile * 64 + ks * 32;
    GLD(s0, base);
    GLD(s1, base + 8192);
  };

  f32x4 acc[8][4] = {};
  bf16x8 aq0[4], aq1[4], bq0[4], bq1[4];

#define GVM4 asm volatile("s_waitcnt vmcnt(4)" ::: "memory")
#define GVM0 asm volatile("s_waitcnt vmcnt(0)" ::: "memory")
#define GNOP

  // Phase: consume (CA,CB) at quadrant CMQ; read-ahead region (TB,TK) quad TM
  // into RA (+RB if RDB); stage; gate; barrier; counted lgkm; MFMA; barrier.
#define PH(CA, CB, CMQ, RA, RB, RDB, TB, TK, TM, STAGE, GATE, LG)            \
  {                                                                          \
    const char* nrb = smem + (TB) * 65536 + (TK) * 32768;                    \
    _Pragma("unroll")                                                        \
    for (int m = 0; m < 4; ++m)                                              \
      RA[m] = *(const bf16x8*)(nrb + offA[TM][m]);                           \
    if (RDB) {                                                               \
      _Pragma("unroll")                                                      \
      for (int n = 0; n < 4; ++n)                                            \
        RB[n] = *(const bf16x8*)(nrb + offB[n]);                             \
    }                                                                        \
    STAGE;                                                                   \
    __builtin_amdgcn_sched_barrier(0);                                       \
    GATE;                                                                    \
    __builtin_amdgcn_s_barrier();                                            \
    asm volatile("s_waitcnt lgkmcnt(" #LG ")" ::: "memory");                 \
    __builtin_amdgcn_sched_barrier(0);                                       \
    __builtin_amdgcn_s_setprio(1);                                           \
    _Pragma("unroll")                                                        \
    for (int m = 0; m < 4; ++m)                                              \
      _Pragma("unroll")                                                      \
      for (int n = 0; n < 4; ++n)                                            \
        acc[(CMQ) * 4 + m][n] = __builtin_amdgcn_mfma_f32_16x16x32_bf16(     \
            CA[m], CB[n], acc[(CMQ) * 4 + m][n], 0, 0, 0);                   \
    __builtin_amdgcn_s_setprio(0);                                           \
    __builtin_amdgcn_s_barrier();                                            \
  }

  // prologue: stage buf0k0, buf0k1 (t=0), buf1k0 (t=1) = 12 loads;
  // retire through buf0k1.B (keep newest 4 = buf1k0); barrier; pre-read p1.
  stagePart(0, 0, 0, 0); stagePart(0, 0, 1, 0);
  stagePart(0, 1, 0, 0); stagePart(0, 1, 1, 0);
  stagePart(1, 0, 0, 1); stagePart(1, 0, 1, 1);
  asm volatile("s_waitcnt vmcnt(4)" ::: "memory");
  __builtin_amdgcn_s_barrier();
#pragma unroll
  for (int m = 0; m < 4; ++m) aq1[m] = *(const bf16x8*)(smem + offA[0][m]);
#pragma unroll
  for (int n = 0; n < 4; ++n) bq0[n] = *(const bf16x8*)(smem + offB[n]);

  for (int i = 0; i < NIT - 1; ++i) {
    const int t0 = 2 * i;
    PH(aq1, bq0, 0, aq0, bq1, 0, 0, 0, 1, stagePart(1, 1, 0, t0 + 1), GVM4, 4)
    PH(aq0, bq0, 1, aq1, bq1, 1, 0, 1, 0, stagePart(1, 1, 1, t0 + 1), GNOP, 8)
    PH(aq1, bq1, 0, aq0, bq0, 0, 0, 1, 1, stagePart(0, 0, 0, t0 + 2), GVM4, 4)
    PH(aq0, bq1, 1, aq1, bq0, 1, 1, 0, 0, stagePart(0, 0, 1, t0 + 2), GNOP, 8)
    PH(aq1, bq0, 0, aq0, bq1, 0, 1, 0, 1, stagePart(0, 1, 0, t0 + 2), GVM4, 4)
    PH(aq0, bq0, 1, aq1, bq1, 1, 1, 1, 0, stagePart(0, 1, 1, t0 + 2), GNOP, 8)
    PH(aq1, bq1, 0, aq0, bq0, 0, 1, 1, 1, stagePart(1, 0, 0, t0 + 3), GVM4, 4)
    PH(aq0, bq1, 1, aq1, bq0, 1, 0, 0, 0, stagePart(1, 0, 1, t0 + 3), GNOP, 8)
  }

  // peeled last iteration (t0 = NT-2): p1,p2 still stage buf1k1@NT-1;
  // gates taper 4 -> 4 -> 0; p8 read-ahead targets stale buf0k0 (unused).
  {
    const int t0 = NT - 2;
    PH(aq1, bq0, 0, aq0, bq1, 0, 0, 0, 1, stagePart(1, 1, 0, t0 + 1), GVM4, 4)
    PH(aq0, bq0, 1, aq1, bq1, 1, 0, 1, 0, stagePart(1, 1, 1, t0 + 1), GNOP, 8)
    PH(aq1, bq1, 0, aq0, bq0, 0, 0, 1, 1, GNOP, GVM4, 4)
    PH(aq0, bq1, 1, aq1, bq0, 1, 1, 0, 0, GNOP, GNOP, 8)
    PH(aq1, bq0, 0, aq0, bq1, 0, 1, 0, 1, GNOP, GVM0, 4)
    PH(aq0, bq0, 1, aq1, bq1, 1, 1, 1, 0, GNOP, GNOP, 8)
    PH(aq1, bq1, 0, aq0, bq0, 0, 1, 1, 1, GNOP, GNOP, 4)
    PH(aq0, bq1, 1, aq1, bq0, 1, 0, 0, 0, GNOP, GNOP, 8)
  }
#undef PH
#undef GLD
#undef GVM4
#undef GVM0
#undef GNOP

  // epilogue: C/D layout col=lane&15, row=(lane>>4)*4+j (m89-verified)
#pragma unroll
  for (int h = 0; h < 8; ++h)
#pragma unroll
    for (int n = 0; n < 4; ++n) {
      const int col = bn + wc + n * 16 + fr;
#pragma unroll
      for (int j = 0; j < 4; ++j) {
        const int row = bm + wr + h * 16 + (lane >> 4) * 4 + j;
        C[(size_t)row * OUT_DIM + col] = acc[h][n][j];
      }
    }
}

// ---------------------------------------------------------------------------
extern "C" void kernel_launch(void* const* d_in, const int* in_sizes, int n_in,
                              void* d_out, int out_size, void* d_ws, size_t ws_size,
                              hipStream_t stream) {
  const float* x        = (const float*)d_in[0];
  const float* codebook = (const float*)d_in[1];
  const float* scales   = (const float*)d_in[2];
  const int*   indices  = (const int*)d_in[3];
  const int*   signs    = (const int*)d_in[4];
  float* out = (float*)d_out;

  u16* W  = (u16*)d_ws;
  u16* Xb = (u16*)d_ws + (size_t)OUT_DIM * IN_DIM;

  (void)hipFuncSetAttribute((const void*)gemm_bt_kernel,
                            hipFuncAttributeMaxDynamicSharedMemorySize, 131072);

  build_w_kernel<<<OUT_DIM, 256, 0, stream>>>(codebook, scales, indices, signs, W);
  cvt_x_kernel<<<2048, 256, 0, stream>>>(x, Xb);
  gemm_bt_kernel<<<(M_DIM / 256) * (OUT_DIM / 256), 512, 131072, stream>>>(Xb, W, out);
}

// Round 8
// 314.684 us; speedup vs baseline: 1.0040x; 1.0040x over previous
//
#include <hip/hip_runtime.h>
#include <hip/hip_bf16.h>

typedef unsigned short u16;
typedef unsigned int u32;
typedef float f32x4 __attribute__((ext_vector_type(4)));
typedef float f32x16 __attribute__((ext_vector_type(16)));
typedef u16 u16x4 __attribute__((ext_vector_type(4)));
typedef u16 u16x8 __attribute__((ext_vector_type(8)));
typedef __bf16 bf16x8 __attribute__((ext_vector_type(8)));

#define OUT_DIM 4096
#define IN_DIM  4096
#define M_DIM   8192   // 4 * 2048

__device__ __forceinline__ u16 f2bf(float f) {
  u32 u = __builtin_bit_cast(u32, f);
  return (u16)((u + 0x7FFFu + ((u >> 16) & 1u)) >> 16);
}

// ---------------------------------------------------------------------------
// W build: codebook gather + sign unpack + 2-level inverse Haar + scale -> bf16
// ---------------------------------------------------------------------------
__global__ __launch_bounds__(256) void build_w_kernel(
    const float* __restrict__ codebook, const float* __restrict__ scales,
    const int* __restrict__ indices, const int* __restrict__ signs,
    u16* __restrict__ W) {
  __shared__ float c[IN_DIM];
  const int o   = blockIdx.x;
  const int tid = threadIdx.x;
  for (int g = tid; g < IN_DIM / 8; g += 256) {
    const int idx = indices[o * (IN_DIM / 8) + g];
    const int sp  = signs[o * (IN_DIM / 8) + g];
    f32x4 c0 = *(const f32x4*)&codebook[idx * 8];
    f32x4 c1 = *(const f32x4*)&codebook[idx * 8 + 4];
    float v[8] = {c0[0], c0[1], c0[2], c0[3], c1[0], c1[1], c1[2], c1[3]};
#pragma unroll
    for (int j = 0; j < 8; ++j)
      c[g * 8 + j] = ((sp >> j) & 1) ? v[j] : -v[j];
  }
  __syncthreads();
  const float scale = scales[o];
  const float S = 0.70710678118654752440f;
  for (int t = tid; t < IN_DIM / 4; t += 256) {
    float a   = c[t];
    float d1  = c[IN_DIM / 4 + t];
    float d2a = c[IN_DIM / 2 + 2 * t];
    float d2b = c[IN_DIM / 2 + 2 * t + 1];
    float e  = (a + d1) * S;
    float od = (a - d1) * S;
    u16x4 w;
    w[0] = f2bf((e  + d2a) * S * scale);
    w[1] = f2bf((e  - d2a) * S * scale);
    w[2] = f2bf((od + d2b) * S * scale);
    w[3] = f2bf((od - d2b) * S * scale);
    *(u16x4*)&W[(size_t)o * IN_DIM + 4 * t] = w;
  }
}

// ---------------------------------------------------------------------------
// X f32 -> bf16
// ---------------------------------------------------------------------------
__global__ __launch_bounds__(256) void cvt_x_kernel(
    const float* __restrict__ X, u16* __restrict__ Xb) {
  const int stride = gridDim.x * blockDim.x;
  const int n8 = (M_DIM * IN_DIM) / 8;
  for (int i = blockIdx.x * blockDim.x + threadIdx.x; i < n8; i += stride) {
    f32x4 a = *(const f32x4*)&X[(size_t)i * 8];
    f32x4 b = *(const f32x4*)&X[(size_t)i * 8 + 4];
    u16x8 r;
    r[0] = f2bf(a[0]); r[1] = f2bf(a[1]); r[2] = f2bf(a[2]); r[3] = f2bf(a[3]);
    r[4] = f2bf(b[0]); r[5] = f2bf(b[1]); r[6] = f2bf(b[2]); r[7] = f2bf(b[3]);
    *(u16x8*)&Xb[(size_t)i * 8] = r;
  }
}

// ---------------------------------------------------------------------------
// GEMM: C[M][N] f32 = A[M][K](bf16) x B[N][K](bf16, B^T layout).
// R8 = R6 skeleton (best, 249us) with two changes:
//  (1) MFMA shape 16x16x32 -> 32x32x16 (measured 2382 vs 2075 TF rate; half
//      the instructions per phase). Wave tile 128x64 = 4 Mfrag x 2 Nfrag,
//      acc = 4x2 f32x16. A/B loaded with the SYMMETRIC mapping
//      row=lane&31, kB=(lane>>5)*16 (k-permutation cancels A vs B);
//      C/D: col=lane&31, row=(reg&3)+8*(reg>>2)+4*(lane>>5) (m74/m101).
//  (2) removed the explicit lgkmcnt(0) wall — plain-C++ ds_reads get
//      compiler-counted lgkm waits, draining DURING the MFMA cluster.
// Unchanged from R6: 8 phases/2 K-tiles, BK=64, ring-2 x 64 KiB LDS, region
// k-slab layout, stage schedule, vmcnt(4) gates at phases 4/8 w/ taper,
// involution swizzle o^=((o>>3)&0x30) (0 conflicts), XCD swizzle, setprio.
// ---------------------------------------------------------------------------
__global__ __launch_bounds__(512, 1) void gemm_bt_kernel(
    const u16* __restrict__ A,   // [M_DIM][K]
    const u16* __restrict__ B,   // [OUT_DIM][K]
    float*     __restrict__ C) { // [M_DIM][OUT_DIM]
  constexpr int K   = IN_DIM;
  constexpr int NT  = K / 64;    // 64 K-tiles (BK=64)
  constexpr int NIT = NT / 2;    // 32 iterations (2 K-tiles each)
  extern __shared__ char smem[]; // 131072 B

  const int tid  = threadIdx.x;
  const int wave = tid >> 6;
  const int lane = tid & 63;

  // XCD-aware bijective swizzle (grid = 512, %8 == 0)
  const int swz = (blockIdx.x & 7) * 64 + (blockIdx.x >> 3);
  const int bm = (swz >> 4) * 256;   // 32 M-blocks
  const int bn = (swz & 15) * 256;   // 16 N-blocks

  const int wr = (wave >> 2) * 128;  // 2 M-wave-groups
  const int wc = (wave & 3) * 64;    // 4 N-wave-groups
  const int r32  = lane & 31;        // fragment row (32-row frags)
  const int kHB  = (lane >> 5) * 16; // k-half byte offset within 32B kstep

  // swizzled read offsets within a 16 KiB region (row stride 64 B)
  // offA[mq][mi][ks2], offB[nf][ks2]
  int offA[2][2][2], offB[2][2];
#pragma unroll
  for (int mq = 0; mq < 2; ++mq)
#pragma unroll
    for (int mi = 0; mi < 2; ++mi)
#pragma unroll
      for (int ks2 = 0; ks2 < 2; ++ks2) {
        int o = (wr + (mq * 2 + mi) * 32 + r32) * 64 + ks2 * 32 + kHB;
        offA[mq][mi][ks2] = o ^ ((o >> 3) & 0x30);
      }
#pragma unroll
  for (int nf = 0; nf < 2; ++nf)
#pragma unroll
    for (int ks2 = 0; ks2 < 2; ++ks2) {
      int o = (wc + nf * 32 + r32) * 64 + ks2 * 32 + kHB;
      offB[nf][ks2] = 16384 + (o ^ ((o >> 3) & 0x30));
    }

  // pre-swizzled global stage sources (inverse involution)
  const int d0 = tid * 16,        d1 = 8192 + tid * 16;
  const int l0 = d0 ^ ((d0 >> 3) & 0x30), l1 = d1 ^ ((d1 >> 3) & 0x30);
  const u16* srcA0 = A + (size_t)(bm + (d0 >> 6)) * K + ((l0 & 63) >> 1);
  const u16* srcA1 = A + (size_t)(bm + (d1 >> 6)) * K + ((l1 & 63) >> 1);
  const u16* srcB0 = B + (size_t)(bn + (d0 >> 6)) * K + ((l0 & 63) >> 1);
  const u16* srcB1 = B + (size_t)(bn + (d1 >> 6)) * K + ((l1 & 63) >> 1);
  const int ldsW = wave * 1024;  // wave-uniform dest base (HW adds lane*16)

#define GLD(SRC, DST)                                              \
  __builtin_amdgcn_global_load_lds(                                \
      (const __attribute__((address_space(1))) void*)(SRC),        \
      (__attribute__((address_space(3))) void*)(DST), 16, 0, 0)

  // stage one 16 KiB region-part: part 0 = A-slab, part 1 = B-slab
  auto stagePart = [&](int bufi, int ks, int part, int tile) {
    char* base = smem + bufi * 65536 + ks * 32768 + part * 16384 + ldsW;
    const u16* s0 = (part ? srcB0 : srcA0) + tile * 64 + ks * 32;
    const u16* s1 = (part ? srcB1 : srcA1) + tile * 64 + ks * 32;
    GLD(s0, base);
    GLD(s1, base + 8192);
  };

  f32x16 acc[4][2] = {};
  bf16x8 aq[2][2], bq[2][2];

  // prologue: T0.k0(A,B), T0.k1(A,B), T1.k0(A,B) = 12 loads; retire T0 fully
  stagePart(0, 0, 0, 0); stagePart(0, 0, 1, 0);
  stagePart(0, 1, 0, 0); stagePart(0, 1, 1, 0);
  stagePart(1, 0, 0, 1); stagePart(1, 0, 1, 1);
  asm volatile("s_waitcnt vmcnt(4)" ::: "memory");
  __builtin_amdgcn_s_barrier();

#define PHASE(BUFI, KS, MQ, READB, STAGE, GATE)                              \
  {                                                                          \
    const char* rb = smem + (BUFI) * 65536 + (KS) * 32768;                   \
    if (READB) {                                                             \
      _Pragma("unroll")                                                      \
      for (int nf = 0; nf < 2; ++nf)                                         \
        _Pragma("unroll")                                                    \
        for (int ks2 = 0; ks2 < 2; ++ks2)                                    \
          bq[nf][ks2] = *(const bf16x8*)(rb + offB[nf][ks2]);                \
    }                                                                        \
    _Pragma("unroll")                                                        \
    for (int mi = 0; mi < 2; ++mi)                                           \
      _Pragma("unroll")                                                      \
      for (int ks2 = 0; ks2 < 2; ++ks2)                                      \
        aq[mi][ks2] = *(const bf16x8*)(rb + offA[MQ][mi][ks2]);              \
    STAGE;                                                                   \
    __builtin_amdgcn_s_barrier();                                            \
    __builtin_amdgcn_s_setprio(1);                                           \
    _Pragma("unroll")                                                        \
    for (int ks2 = 0; ks2 < 2; ++ks2)                                        \
      _Pragma("unroll")                                                      \
      for (int mi = 0; mi < 2; ++mi)                                         \
        _Pragma("unroll")                                                    \
        for (int nf = 0; nf < 2; ++nf)                                       \
          acc[(MQ) * 2 + mi][nf] = __builtin_amdgcn_mfma_f32_32x32x16_bf16(  \
              aq[mi][ks2], bq[nf][ks2], acc[(MQ) * 2 + mi][nf], 0, 0, 0);    \
    __builtin_amdgcn_s_setprio(0);                                           \
    GATE;                                                                    \
    __builtin_amdgcn_s_barrier();                                            \
  }

  for (int i = 0; i < NIT; ++i) {
    const int t0 = 2 * i;
    const bool more = (i < NIT - 1);
    // phases 1-4: consume buf0 (tile t0); phases 5-8: buf1 (tile t0+1)
    PHASE(0, 0, 0, 1, stagePart(1, 1, 0, t0 + 1), )
    PHASE(0, 0, 1, 0, stagePart(1, 1, 1, t0 + 1), )
    PHASE(0, 1, 0, 1, if (more) stagePart(0, 0, 0, t0 + 2), )
    PHASE(0, 1, 1, 0, if (more) stagePart(0, 0, 1, t0 + 2),
          if (more) { asm volatile("s_waitcnt vmcnt(4)" ::: "memory"); }
          else      { asm volatile("s_waitcnt vmcnt(0)" ::: "memory"); })
    PHASE(1, 0, 0, 1, if (more) stagePart(0, 1, 0, t0 + 2), )
    PHASE(1, 0, 1, 0, if (more) stagePart(0, 1, 1, t0 + 2), )
    PHASE(1, 1, 0, 1, if (more) stagePart(1, 0, 0, t0 + 3), )
    PHASE(1, 1, 1, 0, if (more) stagePart(1, 0, 1, t0 + 3),
          if (more) { asm volatile("s_waitcnt vmcnt(4)" ::: "memory"); }
          else      { asm volatile("s_waitcnt vmcnt(0)" ::: "memory"); })
  }
#undef PHASE
#undef GLD

  // epilogue: C/D 32x32 layout col=lane&31, row=(reg&3)+8*(reg>>2)+4*(lane>>5)
#pragma unroll
  for (int mf = 0; mf < 4; ++mf)
#pragma unroll
    for (int nf = 0; nf < 2; ++nf) {
      const int col = bn + wc + nf * 32 + r32;
      const int rbase = bm + wr + mf * 32 + 4 * (lane >> 5);
#pragma unroll
      for (int reg = 0; reg < 16; ++reg) {
        const int row = rbase + (reg & 3) + 8 * (reg >> 2);
        C[(size_t)row * OUT_DIM + col] = acc[mf][nf][reg];
      }
    }
}

// ---------------------------------------------------------------------------
extern "C" void kernel_launch(void* const* d_in, const int* in_sizes, int n_in,
                              void* d_out, int out_size, void* d_ws, size_t ws_size,
                              hipStream_t stream) {
  const float* x        = (const float*)d_in[0];
  const float* codebook = (const float*)d_in[1];
  const float* scales   = (const float*)d_in[2];
  const int*   indices  = (const int*)d_in[3];
  const int*   signs    = (const int*)d_in[4];
  float* out = (float*)d_out;

  u16* W  = (u16*)d_ws;
  u16* Xb = (u16*)d_ws + (size_t)OUT_DIM * IN_DIM;

  (void)hipFuncSetAttribute((const void*)gemm_bt_kernel,
                            hipFuncAttributeMaxDynamicSharedMemorySize, 131072);

  build_w_kernel<<<OUT_DIM, 256, 0, stream>>>(codebook, scales, indices, signs, W);
  cvt_x_kernel<<<2048, 256, 0, stream>>>(x, Xb);
  gemm_bt_kernel<<<(M_DIM / 256) * (OUT_DIM / 256), 512, 131072, stream>>>(Xb, W, out);
}

// Round 9
// 291.121 us; speedup vs baseline: 1.0853x; 1.0809x over previous
//
#include <hip/hip_runtime.h>
#include <hip/hip_bf16.h>

typedef unsigned short u16;
typedef unsigned int u32;
typedef float f32x4 __attribute__((ext_vector_type(4)));
typedef u16 u16x4 __attribute__((ext_vector_type(4)));
typedef u16 u16x8 __attribute__((ext_vector_type(8)));
typedef __bf16 bf16x8 __attribute__((ext_vector_type(8)));

#define OUT_DIM 4096
#define IN_DIM  4096
#define M_DIM   8192   // 4 * 2048

__device__ __forceinline__ u16 f2bf(float f) {
  u32 u = __builtin_bit_cast(u32, f);
  return (u16)((u + 0x7FFFu + ((u >> 16) & 1u)) >> 16);
}

// ---------------------------------------------------------------------------
// W build: codebook gather + sign unpack + 2-level inverse Haar + scale -> bf16
// ---------------------------------------------------------------------------
__global__ __launch_bounds__(256) void build_w_kernel(
    const float* __restrict__ codebook, const float* __restrict__ scales,
    const int* __restrict__ indices, const int* __restrict__ signs,
    u16* __restrict__ W) {
  __shared__ float c[IN_DIM];
  const int o   = blockIdx.x;
  const int tid = threadIdx.x;
  for (int g = tid; g < IN_DIM / 8; g += 256) {
    const int idx = indices[o * (IN_DIM / 8) + g];
    const int sp  = signs[o * (IN_DIM / 8) + g];
    f32x4 c0 = *(const f32x4*)&codebook[idx * 8];
    f32x4 c1 = *(const f32x4*)&codebook[idx * 8 + 4];
    float v[8] = {c0[0], c0[1], c0[2], c0[3], c1[0], c1[1], c1[2], c1[3]};
#pragma unroll
    for (int j = 0; j < 8; ++j)
      c[g * 8 + j] = ((sp >> j) & 1) ? v[j] : -v[j];
  }
  __syncthreads();
  const float scale = scales[o];
  const float S = 0.70710678118654752440f;
  for (int t = tid; t < IN_DIM / 4; t += 256) {
    float a   = c[t];
    float d1  = c[IN_DIM / 4 + t];
    float d2a = c[IN_DIM / 2 + 2 * t];
    float d2b = c[IN_DIM / 2 + 2 * t + 1];
    float e  = (a + d1) * S;
    float od = (a - d1) * S;
    u16x4 w;
    w[0] = f2bf((e  + d2a) * S * scale);
    w[1] = f2bf((e  - d2a) * S * scale);
    w[2] = f2bf((od + d2b) * S * scale);
    w[3] = f2bf((od - d2b) * S * scale);
    *(u16x4*)&W[(size_t)o * IN_DIM + 4 * t] = w;
  }
}

// ---------------------------------------------------------------------------
// X f32 -> bf16
// ---------------------------------------------------------------------------
__global__ __launch_bounds__(256) void cvt_x_kernel(
    const float* __restrict__ X, u16* __restrict__ Xb) {
  const int stride = gridDim.x * blockDim.x;
  const int n8 = (M_DIM * IN_DIM) / 8;
  for (int i = blockIdx.x * blockDim.x + threadIdx.x; i < n8; i += stride) {
    f32x4 a = *(const f32x4*)&X[(size_t)i * 8];
    f32x4 b = *(const f32x4*)&X[(size_t)i * 8 + 4];
    u16x8 r;
    r[0] = f2bf(a[0]); r[1] = f2bf(a[1]); r[2] = f2bf(a[2]); r[3] = f2bf(a[3]);
    r[4] = f2bf(b[0]); r[5] = f2bf(b[1]); r[6] = f2bf(b[2]); r[7] = f2bf(b[3]);
    *(u16x8*)&Xb[(size_t)i * 8] = r;
  }
}

// ---------------------------------------------------------------------------
// GEMM: C[M][N] f32 = A[M][K](bf16) x B[N][K](bf16, B^T layout).
// R9 = R6 skeleton (best) with ONE change: staging bunched into odd phases
// (p1/p3/p5/p7, one full region A+B = 4 loads each) so that the counted
// vmcnt(4) gates at p4/p8 only ever wait for loads issued >=3 phases
// (~1200cy) earlier — covering the ~900cy HBM-miss latency that R6's gates
// (youngest waited load 2 phases old) exposed.
// Unchanged: 16x16x32 MFMA, BM=BN=256, BK=64, 8 waves (2Mx4N), ring-2 x
// 64 KiB LDS in 4 k-slab regions, involution swizzle o^=((o>>3)&0x30)
// (0 conflicts), lgkmcnt(0) wall (m201-faithful), setprio, XCD swizzle.
// Hazards: phase reads/stages touch disjoint regions (p1 R:b0k0 S:b1k1,
// p3 R:b0k1 S:b0k0, p5 R:b1k0 S:b0k1, p7 R:b1k1 S:b1k0); each staged
// region retires at a gate >=1 barrier before its read (iter0 via
// prologue vmcnt(4); tail via vmcnt(0)@p4 of the peeled last iter).
// ---------------------------------------------------------------------------
__global__ __launch_bounds__(512, 1) void gemm_bt_kernel(
    const u16* __restrict__ A,   // [M_DIM][K]
    const u16* __restrict__ B,   // [OUT_DIM][K]
    float*     __restrict__ C) { // [M_DIM][OUT_DIM]
  constexpr int K   = IN_DIM;
  constexpr int NT  = K / 64;    // 64 K-tiles (BK=64)
  constexpr int NIT = NT / 2;    // 32 iterations (2 K-tiles each)
  extern __shared__ char smem[]; // 131072 B

  const int tid  = threadIdx.x;
  const int wave = tid >> 6;
  const int lane = tid & 63;

  // XCD-aware bijective swizzle (grid = 512, %8 == 0)
  const int swz = (blockIdx.x & 7) * 64 + (blockIdx.x >> 3);
  const int bm = (swz >> 4) * 256;   // 32 M-blocks
  const int bn = (swz & 15) * 256;   // 16 N-blocks

  const int wr  = (wave >> 2) * 128;  // 2 M-wave-groups
  const int wc  = (wave & 3) * 64;    // 4 N-wave-groups
  const int fr  = lane & 15;
  const int fkB = (lane >> 4) * 16;   // k-frag byte offset within 64B slab row

  // swizzled read offsets within a 16 KiB region (row stride 64 B)
  int offA[2][4], offB[4];
#pragma unroll
  for (int mq = 0; mq < 2; ++mq)
#pragma unroll
    for (int m = 0; m < 4; ++m) {
      int o = (wr + mq * 64 + m * 16 + fr) * 64 + fkB;
      offA[mq][m] = o ^ ((o >> 3) & 0x30);
    }
#pragma unroll
  for (int n = 0; n < 4; ++n) {
    int o = (wc + n * 16 + fr) * 64 + fkB;
    offB[n] = 16384 + (o ^ ((o >> 3) & 0x30));
  }

  // pre-swizzled global stage sources (inverse involution)
  const int d0 = tid * 16,        d1 = 8192 + tid * 16;
  const int l0 = d0 ^ ((d0 >> 3) & 0x30), l1 = d1 ^ ((d1 >> 3) & 0x30);
  const u16* srcA0 = A + (size_t)(bm + (d0 >> 6)) * K + ((l0 & 63) >> 1);
  const u16* srcA1 = A + (size_t)(bm + (d1 >> 6)) * K + ((l1 & 63) >> 1);
  const u16* srcB0 = B + (size_t)(bn + (d0 >> 6)) * K + ((l0 & 63) >> 1);
  const u16* srcB1 = B + (size_t)(bn + (d1 >> 6)) * K + ((l1 & 63) >> 1);
  const int ldsW = wave * 1024;  // wave-uniform dest base (HW adds lane*16)

#define GLD(SRC, DST)                                              \
  __builtin_amdgcn_global_load_lds(                                \
      (const __attribute__((address_space(1))) void*)(SRC),        \
      (__attribute__((address_space(3))) void*)(DST), 16, 0, 0)

  // stage one full 32 KiB k-slab region (A-part + B-part = 4 loads)
  auto stageRegion = [&](int bufi, int ks, int tile) {
    char* base = smem + bufi * 65536 + ks * 32768 + ldsW;
    const u16* a0 = srcA0 + tile * 64 + ks * 32;
    const u16* a1 = srcA1 + tile * 64 + ks * 32;
    const u16* b0 = srcB0 + tile * 64 + ks * 32;
    const u16* b1 = srcB1 + tile * 64 + ks * 32;
    GLD(a0, base);
    GLD(a1, base + 8192);
    GLD(b0, base + 16384);
    GLD(b1, base + 24576);
  };

  f32x4 acc[8][4] = {};
  bf16x8 aq[4], bq[4];

  // prologue: buf0k0, buf0k1 (t=0), buf1k0 (t=1) = 12 loads;
  // retire buf0 fully (keep buf1k0's 4 in flight).
  stageRegion(0, 0, 0);
  stageRegion(0, 1, 0);
  stageRegion(1, 0, 1);
  asm volatile("s_waitcnt vmcnt(4)" ::: "memory");
  __builtin_amdgcn_s_barrier();

#define PHASE(BUFI, KS, MQ, READB, STAGE, GATE)                              \
  {                                                                          \
    const char* rb = smem + (BUFI) * 65536 + (KS) * 32768;                   \
    if (READB) {                                                             \
      _Pragma("unroll")                                                      \
      for (int n = 0; n < 4; ++n) bq[n] = *(const bf16x8*)(rb + offB[n]);    \
    }                                                                        \
    _Pragma("unroll")                                                        \
    for (int m = 0; m < 4; ++m) aq[m] = *(const bf16x8*)(rb + offA[MQ][m]);  \
    STAGE;                                                                   \
    __builtin_amdgcn_s_barrier();                                            \
    asm volatile("s_waitcnt lgkmcnt(0)" ::: "memory");                       \
    __builtin_amdgcn_s_setprio(1);                                           \
    _Pragma("unroll")                                                        \
    for (int m = 0; m < 4; ++m)                                              \
      _Pragma("unroll")                                                      \
      for (int n = 0; n < 4; ++n)                                            \
        acc[(MQ) * 4 + m][n] = __builtin_amdgcn_mfma_f32_16x16x32_bf16(      \
            aq[m], bq[n], acc[(MQ) * 4 + m][n], 0, 0, 0);                    \
    __builtin_amdgcn_s_setprio(0);                                           \
    GATE;                                                                    \
    __builtin_amdgcn_s_barrier();                                            \
  }

  for (int i = 0; i < NIT - 1; ++i) {
    const int t0 = 2 * i;
    // p1..p4: consume buf0 (tile t0); p5..p8: buf1 (tile t0+1).
    // stages at odd phases; gates vmcnt(4) wait only loads >=3 phases old.
    PHASE(0, 0, 0, 1, stageRegion(1, 1, t0 + 1), )
    PHASE(0, 0, 1, 0, , )
    PHASE(0, 1, 0, 1, stageRegion(0, 0, t0 + 2), )
    PHASE(0, 1, 1, 0, ,
          asm volatile("s_waitcnt vmcnt(4)" ::: "memory"); )
    PHASE(1, 0, 0, 1, stageRegion(0, 1, t0 + 2), )
    PHASE(1, 0, 1, 0, , )
    PHASE(1, 1, 0, 1, stageRegion(1, 0, t0 + 3), )
    PHASE(1, 1, 1, 0, ,
          asm volatile("s_waitcnt vmcnt(4)" ::: "memory"); )
  }

  // peeled last iteration (t0 = NT-2): only (1,1)@NT-1 still needed;
  // gate vmcnt(0) at p4 covers it (3 phases after issue); no later stages.
  PHASE(0, 0, 0, 1, stageRegion(1, 1, NT - 1), )
  PHASE(0, 0, 1, 0, , )
  PHASE(0, 1, 0, 1, , )
  PHASE(0, 1, 1, 0, ,
        asm volatile("s_waitcnt vmcnt(0)" ::: "memory"); )
  PHASE(1, 0, 0, 1, , )
  PHASE(1, 0, 1, 0, , )
  PHASE(1, 1, 0, 1, , )
  PHASE(1, 1, 1, 0, , )
#undef PHASE
#undef GLD

  // epilogue: C/D layout col=lane&15, row=(lane>>4)*4+j (m89-verified)
#pragma unroll
  for (int h = 0; h < 8; ++h)
#pragma unroll
    for (int n = 0; n < 4; ++n) {
      const int col = bn + wc + n * 16 + fr;
#pragma unroll
      for (int j = 0; j < 4; ++j) {
        const int row = bm + wr + h * 16 + (lane >> 4) * 4 + j;
        C[(size_t)row * OUT_DIM + col] = acc[h][n][j];
      }
    }
}

// ---------------------------------------------------------------------------
extern "C" void kernel_launch(void* const* d_in, const int* in_sizes, int n_in,
                              void* d_out, int out_size, void* d_ws, size_t ws_size,
                              hipStream_t stream) {
  const float* x        = (const float*)d_in[0];
  const float* codebook = (const float*)d_in[1];
  const float* scales   = (const float*)d_in[2];
  const int*   indices  = (const int*)d_in[3];
  const int*   signs    = (const int*)d_in[4];
  float* out = (float*)d_out;

  u16* W  = (u16*)d_ws;
  u16* Xb = (u16*)d_ws + (size_t)OUT_DIM * IN_DIM;

  (void)hipFuncSetAttribute((const void*)gemm_bt_kernel,
                            hipFuncAttributeMaxDynamicSharedMemorySize, 131072);

  build_w_kernel<<<OUT_DIM, 256, 0, stream>>>(codebook, scales, indices, signs, W);
  cvt_x_kernel<<<2048, 256, 0, stream>>>(x, Xb);
  gemm_bt_kernel<<<(M_DIM / 256) * (OUT_DIM / 256), 512, 131072, stream>>>(Xb, W, out);
}

// Round 10
// 277.396 us; speedup vs baseline: 1.1390x; 1.0495x over previous
//
#include <hip/hip_runtime.h>
#include <hip/hip_bf16.h>

typedef unsigned short u16;
typedef unsigned int u32;
typedef float f32x4 __attribute__((ext_vector_type(4)));
typedef u16 u16x4 __attribute__((ext_vector_type(4)));
typedef u16 u16x8 __attribute__((ext_vector_type(8)));
typedef __bf16 bf16x8 __attribute__((ext_vector_type(8)));

#define OUT_DIM 4096
#define IN_DIM  4096
#define M_DIM   8192   // 4 * 2048

__device__ __forceinline__ u16 f2bf(float f) {
  u32 u = __builtin_bit_cast(u32, f);
  return (u16)((u + 0x7FFFu + ((u >> 16) & 1u)) >> 16);
}

// ---------------------------------------------------------------------------
// W build: codebook gather + sign unpack + 2-level inverse Haar + scale -> bf16
// ---------------------------------------------------------------------------
__global__ __launch_bounds__(256) void build_w_kernel(
    const float* __restrict__ codebook, const float* __restrict__ scales,
    const int* __restrict__ indices, const int* __restrict__ signs,
    u16* __restrict__ W) {
  __shared__ float c[IN_DIM];
  const int o   = blockIdx.x;
  const int tid = threadIdx.x;
  for (int g = tid; g < IN_DIM / 8; g += 256) {
    const int idx = indices[o * (IN_DIM / 8) + g];
    const int sp  = signs[o * (IN_DIM / 8) + g];
    f32x4 c0 = *(const f32x4*)&codebook[idx * 8];
    f32x4 c1 = *(const f32x4*)&codebook[idx * 8 + 4];
    float v[8] = {c0[0], c0[1], c0[2], c0[3], c1[0], c1[1], c1[2], c1[3]};
#pragma unroll
    for (int j = 0; j < 8; ++j)
      c[g * 8 + j] = ((sp >> j) & 1) ? v[j] : -v[j];
  }
  __syncthreads();
  const float scale = scales[o];
  const float S = 0.70710678118654752440f;
  for (int t = tid; t < IN_DIM / 4; t += 256) {
    float a   = c[t];
    float d1  = c[IN_DIM / 4 + t];
    float d2a = c[IN_DIM / 2 + 2 * t];
    float d2b = c[IN_DIM / 2 + 2 * t + 1];
    float e  = (a + d1) * S;
    float od = (a - d1) * S;
    u16x4 w;
    w[0] = f2bf((e  + d2a) * S * scale);
    w[1] = f2bf((e  - d2a) * S * scale);
    w[2] = f2bf((od + d2b) * S * scale);
    w[3] = f2bf((od - d2b) * S * scale);
    *(u16x4*)&W[(size_t)o * IN_DIM + 4 * t] = w;
  }
}

// ---------------------------------------------------------------------------
// X f32 -> bf16
// ---------------------------------------------------------------------------
__global__ __launch_bounds__(256) void cvt_x_kernel(
    const float* __restrict__ X, u16* __restrict__ Xb) {
  const int stride = gridDim.x * blockDim.x;
  const int n8 = (M_DIM * IN_DIM) / 8;
  for (int i = blockIdx.x * blockDim.x + threadIdx.x; i < n8; i += stride) {
    f32x4 a = *(const f32x4*)&X[(size_t)i * 8];
    f32x4 b = *(const f32x4*)&X[(size_t)i * 8 + 4];
    u16x8 r;
    r[0] = f2bf(a[0]); r[1] = f2bf(a[1]); r[2] = f2bf(a[2]); r[3] = f2bf(a[3]);
    r[4] = f2bf(b[0]); r[5] = f2bf(b[1]); r[6] = f2bf(b[2]); r[7] = f2bf(b[3]);
    *(u16x8*)&Xb[(size_t)i * 8] = r;
  }
}

// ---------------------------------------------------------------------------
// GEMM: C[M][N] f32 = A[M][K](bf16) x B[N][K](bf16, B^T layout).
// R10 = R6 with ONE structural change: SINGLE barrier per phase (8/iter vs
// 16). Phase = [reads][stage][gate][barrier][lgkm0][MFMA] — no trailing
// barrier, so the LDS-port work (ds_reads) of phase p+1 overlaps the MFMA
// cluster of phase p (the two were measured co-critical: ~580 + ~620 cy).
// Safety: all reads of phase r complete before barrier(r+1) (each wave's
// lgkm-wait(r) precedes its reads(r+1) which precede barrier(r+1)); every
// stage targets a region last read 2 phases earlier -> issued post-
// barrier(lastread+1) -> no write/read race. Stages at even phases:
// p2:(1,1)@t+1  p4:(0,0)@t+2  p6:(0,1)@t+2  p8:(1,0)@t+3; gates vmcnt(8)
// at every even phase (youngest waited group is 4 phases ~2000cy old);
// tail tapers vm8/vm8/vm4/vm0. Max 12 loads in flight, never vmcnt(0) in
// steady state. Unchanged: 16x16x32 MFMA, BM=BN=256, BK=64, 8 waves
// (2Mx4N), ring-2 x 64 KiB LDS k-slab regions, involution swizzle
// o^=((o>>3)&0x30) (0 conflicts), setprio, XCD swizzle.
// ---------------------------------------------------------------------------
__global__ __launch_bounds__(512, 1) void gemm_bt_kernel(
    const u16* __restrict__ A,   // [M_DIM][K]
    const u16* __restrict__ B,   // [OUT_DIM][K]
    float*     __restrict__ C) { // [M_DIM][OUT_DIM]
  constexpr int K   = IN_DIM;
  constexpr int NT  = K / 64;    // 64 K-tiles (BK=64)
  constexpr int NIT = NT / 2;    // 32 iterations (2 K-tiles each)
  extern __shared__ char smem[]; // 131072 B

  const int tid  = threadIdx.x;
  const int wave = tid >> 6;
  const int lane = tid & 63;

  // XCD-aware bijective swizzle (grid = 512, %8 == 0)
  const int swz = (blockIdx.x & 7) * 64 + (blockIdx.x >> 3);
  const int bm = (swz >> 4) * 256;   // 32 M-blocks
  const int bn = (swz & 15) * 256;   // 16 N-blocks

  const int wr  = (wave >> 2) * 128;  // 2 M-wave-groups
  const int wc  = (wave & 3) * 64;    // 4 N-wave-groups
  const int fr  = lane & 15;
  const int fkB = (lane >> 4) * 16;   // k-frag byte offset within 64B slab row

  // swizzled read offsets within a 16 KiB region (row stride 64 B)
  int offA[2][4], offB[4];
#pragma unroll
  for (int mq = 0; mq < 2; ++mq)
#pragma unroll
    for (int m = 0; m < 4; ++m) {
      int o = (wr + mq * 64 + m * 16 + fr) * 64 + fkB;
      offA[mq][m] = o ^ ((o >> 3) & 0x30);
    }
#pragma unroll
  for (int n = 0; n < 4; ++n) {
    int o = (wc + n * 16 + fr) * 64 + fkB;
    offB[n] = 16384 + (o ^ ((o >> 3) & 0x30));
  }

  // pre-swizzled global stage sources (inverse involution)
  const int d0 = tid * 16,        d1 = 8192 + tid * 16;
  const int l0 = d0 ^ ((d0 >> 3) & 0x30), l1 = d1 ^ ((d1 >> 3) & 0x30);
  const u16* srcA0 = A + (size_t)(bm + (d0 >> 6)) * K + ((l0 & 63) >> 1);
  const u16* srcA1 = A + (size_t)(bm + (d1 >> 6)) * K + ((l1 & 63) >> 1);
  const u16* srcB0 = B + (size_t)(bn + (d0 >> 6)) * K + ((l0 & 63) >> 1);
  const u16* srcB1 = B + (size_t)(bn + (d1 >> 6)) * K + ((l1 & 63) >> 1);
  const int ldsW = wave * 1024;  // wave-uniform dest base (HW adds lane*16)

#define GLD(SRC, DST)                                              \
  __builtin_amdgcn_global_load_lds(                                \
      (const __attribute__((address_space(1))) void*)(SRC),        \
      (__attribute__((address_space(3))) void*)(DST), 16, 0, 0)

  // stage one full 32 KiB k-slab region (A-part + B-part = 4 loads)
  auto stageRegion = [&](int bufi, int ks, int tile) {
    char* base = smem + bufi * 65536 + ks * 32768 + ldsW;
    const u16* a0 = srcA0 + tile * 64 + ks * 32;
    const u16* a1 = srcA1 + tile * 64 + ks * 32;
    const u16* b0 = srcB0 + tile * 64 + ks * 32;
    const u16* b1 = srcB1 + tile * 64 + ks * 32;
    GLD(a0, base);
    GLD(a1, base + 8192);
    GLD(b0, base + 16384);
    GLD(b1, base + 24576);
  };

  f32x4 acc[8][4] = {};
  bf16x8 aq[4], bq[4];

  // prologue: (0,0)@0, (0,1)@0, (1,0)@1 = 12 loads; retire (0,0) only.
  stageRegion(0, 0, 0);
  stageRegion(0, 1, 0);
  stageRegion(1, 0, 1);
  asm volatile("s_waitcnt vmcnt(8)" ::: "memory");
  __builtin_amdgcn_s_barrier();

  // single-barrier phase: reads; stage; gate; barrier; lgkm0; MFMA.
#define PHASE(BUFI, KS, MQ, READB, STAGE, GATE)                              \
  {                                                                          \
    const char* rb = smem + (BUFI) * 65536 + (KS) * 32768;                   \
    if (READB) {                                                             \
      _Pragma("unroll")                                                      \
      for (int n = 0; n < 4; ++n) bq[n] = *(const bf16x8*)(rb + offB[n]);    \
    }                                                                        \
    _Pragma("unroll")                                                        \
    for (int m = 0; m < 4; ++m) aq[m] = *(const bf16x8*)(rb + offA[MQ][m]);  \
    STAGE;                                                                   \
    GATE;                                                                    \
    __builtin_amdgcn_s_barrier();                                            \
    asm volatile("s_waitcnt lgkmcnt(0)" ::: "memory");                       \
    __builtin_amdgcn_s_setprio(1);                                           \
    _Pragma("unroll")                                                        \
    for (int m = 0; m < 4; ++m)                                              \
      _Pragma("unroll")                                                      \
      for (int n = 0; n < 4; ++n)                                            \
        acc[(MQ) * 4 + m][n] = __builtin_amdgcn_mfma_f32_16x16x32_bf16(      \
            aq[m], bq[n], acc[(MQ) * 4 + m][n], 0, 0, 0);                    \
    __builtin_amdgcn_s_setprio(0);                                           \
  }

#define VM8 asm volatile("s_waitcnt vmcnt(8)" ::: "memory")
#define VM4 asm volatile("s_waitcnt vmcnt(4)" ::: "memory")
#define VM0 asm volatile("s_waitcnt vmcnt(0)" ::: "memory")

  for (int i = 0; i < NIT - 1; ++i) {
    const int t0 = 2 * i;
    PHASE(0, 0, 0, 1, , )
    PHASE(0, 0, 1, 0, stageRegion(1, 1, t0 + 1), VM8)
    PHASE(0, 1, 0, 1, , )
    PHASE(0, 1, 1, 0, stageRegion(0, 0, t0 + 2), VM8)
    PHASE(1, 0, 0, 1, , )
    PHASE(1, 0, 1, 0, stageRegion(0, 1, t0 + 2), VM8)
    PHASE(1, 1, 0, 1, , )
    PHASE(1, 1, 1, 0, stageRegion(1, 0, t0 + 3), VM8)
  }

  // peeled last iteration (t0 = NT-2): only (1,1)@NT-1 still staged;
  // gates taper vm8 / vm4 / vm0 / none.
  PHASE(0, 0, 0, 1, , )
  PHASE(0, 0, 1, 0, stageRegion(1, 1, NT - 1), VM8)
  PHASE(0, 1, 0, 1, , )
  PHASE(0, 1, 1, 0, , VM4)
  PHASE(1, 0, 0, 1, , )
  PHASE(1, 0, 1, 0, , VM0)
  PHASE(1, 1, 0, 1, , )
  PHASE(1, 1, 1, 0, , )
#undef PHASE
#undef GLD
#undef VM8
#undef VM4
#undef VM0

  // epilogue: C/D layout col=lane&15, row=(lane>>4)*4+j (m89-verified)
#pragma unroll
  for (int h = 0; h < 8; ++h)
#pragma unroll
    for (int n = 0; n < 4; ++n) {
      const int col = bn + wc + n * 16 + fr;
#pragma unroll
      for (int j = 0; j < 4; ++j) {
        const int row = bm + wr + h * 16 + (lane >> 4) * 4 + j;
        C[(size_t)row * OUT_DIM + col] = acc[h][n][j];
      }
    }
}

// ---------------------------------------------------------------------------
extern "C" void kernel_launch(void* const* d_in, const int* in_sizes, int n_in,
                              void* d_out, int out_size, void* d_ws, size_t ws_size,
                              hipStream_t stream) {
  const float* x        = (const float*)d_in[0];
  const float* codebook = (const float*)d_in[1];
  const float* scales   = (const float*)d_in[2];
  const int*   indices  = (const int*)d_in[3];
  const int*   signs    = (const int*)d_in[4];
  float* out = (float*)d_out;

  u16* W  = (u16*)d_ws;
  u16* Xb = (u16*)d_ws + (size_t)OUT_DIM * IN_DIM;

  (void)hipFuncSetAttribute((const void*)gemm_bt_kernel,
                            hipFuncAttributeMaxDynamicSharedMemorySize, 131072);

  build_w_kernel<<<OUT_DIM, 256, 0, stream>>>(codebook, scales, indices, signs, W);
  cvt_x_kernel<<<2048, 256, 0, stream>>>(x, Xb);
  gemm_bt_kernel<<<(M_DIM / 256) * (OUT_DIM / 256), 512, 131072, stream>>>(Xb, W, out);
}